// Round 5
// baseline (243.415 us; speedup 1.0000x reference)
//
#include <hip/hip_runtime.h>
#include <hip/hip_cooperative_groups.h>
#include <math.h>
#include <limits.h>

namespace cg = cooperative_groups;

#define NEG_INF -1e9f

// ==================== cooperative fused kernel (max_len == 16, hidden == 256) ====================
// 256 blocks x 256 threads, co-resident (1 block/CU).
// Phase 1: s[e] = dot(emb[e], W)  -- 4 rows in flight per wave (MLP for BW ceiling)
// Phase 2: thread-per-path logits (16-gather ILP), paths STRIDED across blocks
//          so gathers use all 256 CUs; per-block softmax partials. No fences/atomics.
// Phase 3: block 0 combines 256 partials -> p, logprob; z[p] gather.
__global__ __launch_bounds__(256) void k_coop(
    const float* __restrict__ emb, const int* __restrict__ paths,
    const int* __restrict__ path_lens, const int* __restrict__ path_mask,
    const float* __restrict__ W, const float* __restrict__ b,
    float* __restrict__ s, float* __restrict__ pmax, int* __restrict__ pidx,
    float* __restrict__ psum, float* __restrict__ out,
    int n_edges, int n_paths, int max_len)
{
    cg::grid_group grid = cg::this_grid();

    __shared__ float rv[4]; __shared__ int ri[4]; __shared__ float rs[4];
    __shared__ float s_M, s_S; __shared__ int s_P;

    const int tid  = threadIdx.x, lane = tid & 63, wv = tid >> 6;
    const int nblk = (int)gridDim.x;              // 256
    const int gwave = blockIdx.x * 4 + wv;        // 0..1023
    const int nwave = nblk * 4;                   // 1024

    // ---------------- phase 1: edge dots, 4 rows per wave-step ----------------
    {
        const float4  w4   = ((const float4*)W)[lane];
        const float4* emb4 = (const float4*)emb;
        for (int base = gwave * 4; base < n_edges; base += nwave * 4) {
            const int v1 = base + 1 < n_edges, v2 = base + 2 < n_edges,
                      v3 = base + 3 < n_edges;
            float4 r0 = emb4[(size_t)base * 64 + lane];
            float4 r1 = v1 ? emb4[(size_t)(base + 1) * 64 + lane] : make_float4(0,0,0,0);
            float4 r2 = v2 ? emb4[(size_t)(base + 2) * 64 + lane] : make_float4(0,0,0,0);
            float4 r3 = v3 ? emb4[(size_t)(base + 3) * 64 + lane] : make_float4(0,0,0,0);
            float d0 = r0.x*w4.x + r0.y*w4.y + r0.z*w4.z + r0.w*w4.w;
            float d1 = r1.x*w4.x + r1.y*w4.y + r1.z*w4.z + r1.w*w4.w;
            float d2 = r2.x*w4.x + r2.y*w4.y + r2.z*w4.z + r2.w*w4.w;
            float d3 = r3.x*w4.x + r3.y*w4.y + r3.z*w4.z + r3.w*w4.w;
#pragma unroll
            for (int off = 32; off; off >>= 1) {
                d0 += __shfl_down(d0, off, 64);
                d1 += __shfl_down(d1, off, 64);
                d2 += __shfl_down(d2, off, 64);
                d3 += __shfl_down(d3, off, 64);
            }
            if (lane == 0) {
                s[base] = d0;
                if (v1) s[base + 1] = d1;
                if (v2) s[base + 2] = d2;
                if (v3) s[base + 3] = d3;
            }
        }
    }
    grid.sync();                                  // s visible grid-wide

    // ---------------- phase 2: logits + per-block softmax partials ----------------
    {
        const int p = blockIdx.x + nblk * tid;    // strided: block b owns {b, b+256, ...}
        float v = -INFINITY; int vi = INT_MAX;
        if (p < n_paths) {
            vi = p;
            if (path_mask[p] == 0) v = NEG_INF;
            else {
                const int len = path_lens[p] + 1; // 1..16
                const int4* pp4 = (const int4*)(paths + (size_t)p * 16);
                int4 a0 = pp4[0], a1 = pp4[1], a2 = pp4[2], a3 = pp4[3];
                int idx[16] = { a0.x, a0.y, a0.z, a0.w, a1.x, a1.y, a1.z, a1.w,
                                a2.x, a2.y, a2.z, a2.w, a3.x, a3.y, a3.z, a3.w };
                float acc = 0.f;
#pragma unroll
                for (int j = 0; j < 16; ++j) {    // 16 independent gathers, full ILP
                    float t = s[idx[j]];
                    acc += (j < len) ? t : 0.f;
                }
                v = acc / (float)len + b[0];
            }
        }
        // block max + first-index argmax
        float bv = v; int bi = vi;
#pragma unroll
        for (int off = 32; off; off >>= 1) {
            float ov = __shfl_down(bv, off, 64);
            int   oi = __shfl_down(bi, off, 64);
            if (ov > bv || (ov == bv && oi < bi)) { bv = ov; bi = oi; }
        }
        if (lane == 0) { rv[wv] = bv; ri[wv] = bi; }
        __syncthreads();
        if (tid == 0) {
            float bm = rv[0]; int bmi = ri[0];
            for (int w = 1; w < 4; ++w)
                if (rv[w] > bm || (rv[w] == bm && ri[w] < bmi)) { bm = rv[w]; bmi = ri[w]; }
            s_M = bm; s_P = bmi;
        }
        __syncthreads();
        const float bm = s_M;
        float se = (vi == INT_MAX) ? 0.f : expf(v - bm);
#pragma unroll
        for (int off = 32; off; off >>= 1) se += __shfl_down(se, off, 64);
        if (lane == 0) rs[wv] = se;
        __syncthreads();
        if (tid == 0) {
            pmax[blockIdx.x] = s_M;
            pidx[blockIdx.x] = s_P;
            psum[blockIdx.x] = rs[0] + rs[1] + rs[2] + rs[3];
        }
    }
    grid.sync();                                  // partials visible grid-wide
    if (blockIdx.x != 0) return;

    // ---------------- phase 3: block 0 combines 256 partials + z ----------------
    {
        float mv = pmax[tid]; int mi = pidx[tid]; // tid < 256 == nblk
#pragma unroll
        for (int off = 32; off; off >>= 1) {
            float ov = __shfl_down(mv, off, 64);
            int   oi = __shfl_down(mi, off, 64);
            if (ov > mv || (ov == mv && oi < mi)) { mv = ov; mi = oi; }
        }
        if (lane == 0) { rv[wv] = mv; ri[wv] = mi; }
        __syncthreads();
        if (tid == 0) {
            float M = rv[0]; int P = ri[0];
            for (int w = 1; w < 4; ++w)
                if (rv[w] > M || (rv[w] == M && ri[w] < P)) { M = rv[w]; P = ri[w]; }
            s_M = M; s_P = P;
        }
        __syncthreads();
        const float M = s_M; const int P = s_P;

        // S = sum_b psum[b] * exp(pmax[b] - M); empty/all-masked handled by exp->0
        float sp = psum[tid] * expf(pmax[tid] - M);
#pragma unroll
        for (int off = 32; off; off >>= 1) sp += __shfl_down(sp, off, 64);
        if (lane == 0) rs[wv] = sp;
        __syncthreads();
        if (tid == 0) s_S = rs[0] + rs[1] + rs[2] + rs[3];
        __syncthreads();

        // z[P]: 256 threads, one per hidden dim, in-order edge sum
        const int lenP = path_lens[P] + 1;
        const int* pp = paths + (size_t)P * max_len;
        float acc = 0.f;
        for (int j = 0; j < lenP; ++j)
            acc += emb[(size_t)pp[j] * 256 + tid];
        out[2 + tid] = acc / (float)lenP;
        if (tid == 0) { out[0] = (float)P; out[1] = -logf(s_S); }  // l_P == M exactly
    }
}

// ==================== generic fallback (round-1 structure, proven) ====================

__global__ __launch_bounds__(256) void k_edge_dot(
    const float* __restrict__ emb, const float* __restrict__ W,
    float* __restrict__ s, int* __restrict__ counter, int n_edges)
{
    if (blockIdx.x == 0 && threadIdx.x == 0) *counter = 0;
    int wave = (blockIdx.x * (int)blockDim.x + (int)threadIdx.x) >> 6;
    int lane = threadIdx.x & 63;
    if (wave >= n_edges) return;
    const float4 e = ((const float4*)emb)[(size_t)wave * 64 + lane];
    const float4 w = ((const float4*)W)[lane];
    float d = e.x * w.x + e.y * w.y + e.z * w.z + e.w * w.w;
#pragma unroll
    for (int off = 32; off; off >>= 1) d += __shfl_down(d, off, 64);
    if (lane == 0) s[wave] = d;
}

__global__ __launch_bounds__(256) void k_fused_gen(
    const float* __restrict__ s, const int* __restrict__ paths,
    const int* __restrict__ path_lens, const int* __restrict__ path_mask,
    const float* __restrict__ b, const float* __restrict__ emb,
    float* __restrict__ pmax, int* __restrict__ pidx, float* __restrict__ psum,
    int* __restrict__ counter, float* __restrict__ out,
    int n_paths, int max_len)
{
    __shared__ float rv[4]; __shared__ int ri[4]; __shared__ float rs[4];
    __shared__ float s_M, s_S; __shared__ int s_P, s_last;

    const int tid = threadIdx.x, lane = tid & 63, wv = tid >> 6;
    const int p = blockIdx.x * 256 + tid;

    float v = -INFINITY; int vi = INT_MAX;
    if (p < n_paths) {
        vi = p;
        if (path_mask[p] == 0) v = NEG_INF;
        else {
            int len = path_lens[p] + 1;
            const int* pp = paths + (size_t)p * max_len;
            float acc = 0.f;
            for (int j = 0; j < len; ++j) acc += s[pp[j]];
            v = acc / (float)len + b[0];
        }
    }
    float bv = v; int bi = vi;
#pragma unroll
    for (int off = 32; off; off >>= 1) {
        float ov = __shfl_down(bv, off, 64);
        int   oi = __shfl_down(bi, off, 64);
        if (ov > bv || (ov == bv && oi < bi)) { bv = ov; bi = oi; }
    }
    if (lane == 0) { rv[wv] = bv; ri[wv] = bi; }
    __syncthreads();
    if (tid == 0) {
        float mvv = rv[0]; int mii = ri[0];
        for (int w = 1; w < 4; ++w)
            if (rv[w] > mvv || (rv[w] == mvv && ri[w] < mii)) { mvv = rv[w]; mii = ri[w]; }
        s_M = mvv; s_P = mii;
    }
    __syncthreads();
    const float bm = s_M;
    float se = expf(v - bm);
#pragma unroll
    for (int off = 32; off; off >>= 1) se += __shfl_down(se, off, 64);
    if (lane == 0) rs[wv] = se;
    __syncthreads();
    if (tid == 0) {
        pmax[blockIdx.x] = bm;
        pidx[blockIdx.x] = s_P;
        psum[blockIdx.x] = rs[0] + rs[1] + rs[2] + rs[3];
        __threadfence();
        int tk = atomicAdd(counter, 1);
        s_last = (tk == (int)gridDim.x - 1) ? 1 : 0;
    }
    __syncthreads();
    if (!s_last) return;
    __threadfence();

    const int nb = gridDim.x;
    float mv = -INFINITY; int mi = INT_MAX;
    for (int i = tid; i < nb; i += 256) {
        float tv = pmax[i]; int ti = pidx[i];
        if (tv > mv || (tv == mv && ti < mi)) { mv = tv; mi = ti; }
    }
#pragma unroll
    for (int off = 32; off; off >>= 1) {
        float ov = __shfl_down(mv, off, 64);
        int   oi = __shfl_down(mi, off, 64);
        if (ov > mv || (ov == mv && oi < mi)) { mv = ov; mi = oi; }
    }
    if (lane == 0) { rv[wv] = mv; ri[wv] = mi; }
    __syncthreads();
    if (tid == 0) {
        float M = rv[0]; int P = ri[0];
        for (int w = 1; w < 4; ++w)
            if (rv[w] > M || (rv[w] == M && ri[w] < P)) { M = rv[w]; P = ri[w]; }
        s_M = M; s_P = P;
    }
    __syncthreads();
    const float M = s_M; const int P = s_P;
    float sp = 0.f;
    for (int i = tid; i < nb; i += 256)
        sp += psum[i] * expf(pmax[i] - M);
#pragma unroll
    for (int off = 32; off; off >>= 1) sp += __shfl_down(sp, off, 64);
    if (lane == 0) rs[wv] = sp;
    __syncthreads();
    if (tid == 0) s_S = rs[0] + rs[1] + rs[2] + rs[3];
    __syncthreads();

    const int lenP = path_lens[P] + 1;
    const int* pp = paths + (size_t)P * max_len;
    if (tid < 256) {
        float acc = 0.f;
        for (int j = 0; j < lenP; ++j)
            acc += emb[(size_t)pp[j] * 256 + tid];
        out[2 + tid] = acc / (float)lenP;
    }
    if (tid == 0) { out[0] = (float)P; out[1] = -logf(s_S); }
}

// ==================== launcher ====================

extern "C" void kernel_launch(void* const* d_in, const int* in_sizes, int n_in,
                              void* d_out, int out_size, void* d_ws, size_t ws_size,
                              hipStream_t stream) {
    const float* emb       = (const float*)d_in[0];   // [n_edges, 256]
    const int*   paths     = (const int*)  d_in[1];   // [n_paths, max_len]
    const int*   path_lens = (const int*)  d_in[2];   // [n_paths]
    const int*   path_mask = (const int*)  d_in[3];   // [n_paths]
    const float* W         = (const float*)d_in[4];   // [256]
    const float* b         = (const float*)d_in[5];   // [1]

    int hidden  = in_sizes[4];                 // 256
    int n_edges = in_sizes[0] / hidden;        // 100000
    int n_paths = in_sizes[2];                 // 20000
    int max_len = in_sizes[1] / n_paths;       // 16

    float* s = (float*)d_ws;                   // [n_edges]

    if (max_len == 16 && hidden == 256) {
        const int nblk = 256;
        float* pmax = s + n_edges;             // [256]
        float* psum = pmax + nblk;             // [256]
        int*   pidx = (int*)(psum + nblk);     // [256]
        float* outp = (float*)d_out;

        void* args[] = { (void*)&emb, (void*)&paths, (void*)&path_lens,
                         (void*)&path_mask, (void*)&W, (void*)&b,
                         (void*)&s, (void*)&pmax, (void*)&pidx, (void*)&psum,
                         (void*)&outp, (void*)&n_edges, (void*)&n_paths,
                         (void*)&max_len };
        hipLaunchCooperativeKernel((const void*)k_coop, dim3(nblk), dim3(256),
                                   args, 0, stream);
    } else {
        int blocks2 = (n_paths + 255) / 256;
        float* pmax    = s + n_edges;
        float* psum    = pmax + blocks2;
        int*   pidx    = (int*)(psum + blocks2);
        int*   counter = pidx + blocks2;

        int blocks1 = (n_edges * 64 + 255) / 256;
        k_edge_dot<<<blocks1, 256, 0, stream>>>(emb, W, s, counter, n_edges);
        k_fused_gen<<<blocks2, 256, 0, stream>>>(s, paths, path_lens, path_mask,
                                                 b, emb, pmax, pidx, psum, counter,
                                                 (float*)d_out, n_paths, max_len);
    }
}

// Round 6
// 167.559 us; speedup vs baseline: 1.4527x; 1.4527x over previous
//
#include <hip/hip_runtime.h>
#include <math.h>
#include <limits.h>

#define NEG_INF -1e9f

// K1: s[e] = dot(edge_emb[e], W) -- one wave (64 lanes) per 256-float row.
// Memory-floor kernel: reads emb exactly once (102.4 MB), coalesced float4,
// ~82% of HBM peak. (Also zeroes the ticket counter used by the generic
// fallback path; harmless scribble on the fast path.)
__global__ __launch_bounds__(256) void k_edge_dot(
    const float* __restrict__ emb, const float* __restrict__ W,
    float* __restrict__ s, int* __restrict__ counter, int n_edges)
{
    if (blockIdx.x == 0 && threadIdx.x == 0) *counter = 0;
    int wave = (blockIdx.x * (int)blockDim.x + (int)threadIdx.x) >> 6;
    int lane = threadIdx.x & 63;
    if (wave >= n_edges) return;
    const float4 e = ((const float4*)emb)[(size_t)wave * 64 + lane];
    const float4 w = ((const float4*)W)[lane];
    float d = e.x * w.x + e.y * w.y + e.z * w.z + e.w * w.w;
#pragma unroll
    for (int off = 32; off; off >>= 1) d += __shfl_down(d, off, 64);
    if (lane == 0) s[wave] = d;
}

// K2 (max_len == 16): one thread per path, ONE WAVE per block.
// 313 blocks -> ~1.2 blocks/CU across all 256 CUs (vs 79 blocks on 79 CUs):
// the divergent 4B gathers of the L2/L3-resident s-table spread over every
// CU's LSU. Mask short-circuit first; int4 path loads; 16 independent
// clamped gathers (full MLP). No tickets, no fences -- pure compute.
__global__ __launch_bounds__(64) void k_logits16(
    const float* __restrict__ s, const int* __restrict__ paths,
    const int* __restrict__ path_lens, const int* __restrict__ path_mask,
    const float* __restrict__ b, float* __restrict__ logits, int n_paths)
{
    int p = blockIdx.x * 64 + (int)threadIdx.x;
    if (p >= n_paths) return;
    if (path_mask[p] == 0) { logits[p] = NEG_INF; return; }
    int len = path_lens[p] + 1;                 // 1..16
    const int4* pp4 = (const int4*)(paths + (size_t)p * 16);
    int4 a0 = pp4[0], a1 = pp4[1], a2 = pp4[2], a3 = pp4[3];
    int idx[16] = { a0.x, a0.y, a0.z, a0.w, a1.x, a1.y, a1.z, a1.w,
                    a2.x, a2.y, a2.z, a2.w, a3.x, a3.y, a3.z, a3.w };
    float acc = 0.f;
#pragma unroll
    for (int j = 0; j < 16; ++j) {
        float v = s[idx[j]];                    // always in-bounds
        acc += (j < len) ? v : 0.f;
    }
    logits[p] = acc / (float)len + b[0];
}

// Generic fallback logits (max_len != 16)
__global__ __launch_bounds__(64) void k_logits_gen(
    const float* __restrict__ s, const int* __restrict__ paths,
    const int* __restrict__ path_lens, const int* __restrict__ path_mask,
    const float* __restrict__ b, float* __restrict__ logits,
    int n_paths, int max_len)
{
    int p = blockIdx.x * 64 + (int)threadIdx.x;
    if (p >= n_paths) return;
    if (path_mask[p] == 0) { logits[p] = NEG_INF; return; }
    int len = path_lens[p] + 1;
    const int* pp = paths + (size_t)p * max_len;
    float acc = 0.f;
    for (int j = 0; j < len; ++j) acc += s[pp[j]];
    logits[p] = acc / (float)len + b[0];
}

// K3: single block. argmax (first-occurrence tie-break), logsumexp, then
// z[p] with PRELOADED indices (16 independent row-loads, one latency round).
__global__ __launch_bounds__(1024) void k_final(
    const float* __restrict__ logits, const float* __restrict__ emb,
    const int* __restrict__ paths, const int* __restrict__ path_lens,
    float* __restrict__ out, int n_paths, int max_len)
{
    __shared__ float sv[16];
    __shared__ int   si[16];
    __shared__ float ssum[16];
    __shared__ int   s_p, s_len;
    __shared__ float s_max, s_logprob;

    int tid = threadIdx.x, lane = tid & 63, wv = tid >> 6;
    int n4 = n_paths >> 2;
    const float4* l4 = (const float4*)logits;

    // pass 1: block-wide argmax with first-index tie-break (float4 sweep)
    float bv = -INFINITY; int bi = 0x7fffffff;
    for (int i = tid; i < n4; i += 1024) {
        float4 v = l4[i];
        int base = i << 2;
        if (v.x > bv) { bv = v.x; bi = base; }
        if (v.y > bv) { bv = v.y; bi = base + 1; }
        if (v.z > bv) { bv = v.z; bi = base + 2; }
        if (v.w > bv) { bv = v.w; bi = base + 3; }
    }
    for (int i = (n4 << 2) + tid; i < n_paths; i += 1024) {  // tail
        float v = logits[i];
        if (v > bv) { bv = v; bi = i; }
    }
#pragma unroll
    for (int off = 32; off; off >>= 1) {
        float ov = __shfl_down(bv, off, 64);
        int   oi = __shfl_down(bi, off, 64);
        if (ov > bv || (ov == bv && oi < bi)) { bv = ov; bi = oi; }
    }
    if (lane == 0) { sv[wv] = bv; si[wv] = bi; }
    __syncthreads();
    if (tid == 0) {
        float mv = sv[0]; int mi = si[0];
        for (int w = 1; w < 16; ++w)
            if (sv[w] > mv || (sv[w] == mv && si[w] < mi)) { mv = sv[w]; mi = si[w]; }
        s_max = mv; s_p = mi; s_len = path_lens[mi] + 1;
    }
    __syncthreads();
    float mx = s_max;

    // pass 2: sum exp(logits - max);  logp[argmax] = -log(sumexp)
    float se = 0.f;
    for (int i = tid; i < n4; i += 1024) {
        float4 v = l4[i];
        se += expf(v.x - mx) + expf(v.y - mx) + expf(v.z - mx) + expf(v.w - mx);
    }
    for (int i = (n4 << 2) + tid; i < n_paths; i += 1024)
        se += expf(logits[i] - mx);
#pragma unroll
    for (int off = 32; off; off >>= 1) se += __shfl_down(se, off, 64);
    if (lane == 0) ssum[wv] = se;
    __syncthreads();
    if (tid == 0) {
        float t = 0.f;
        for (int w = 0; w < 16; ++w) t += ssum[w];
        s_logprob = -logf(t);
    }
    __syncthreads();

    // z[p]: 256 threads, one per hidden dim. Preload indices -> 16
    // independent clamped loads (ILP) instead of a serial dependent chain.
    int p = s_p, len = s_len;
    if (tid < 256) {
        const int* pp = paths + (size_t)p * max_len;
        float acc = 0.f;
        if (max_len == 16) {
            const int4* pp4 = (const int4*)pp;
            int4 a0 = pp4[0], a1 = pp4[1], a2 = pp4[2], a3 = pp4[3];
            int idx[16] = { a0.x, a0.y, a0.z, a0.w, a1.x, a1.y, a1.z, a1.w,
                            a2.x, a2.y, a2.z, a2.w, a3.x, a3.y, a3.z, a3.w };
#pragma unroll
            for (int j = 0; j < 16; ++j) {
                int e = (j < len) ? idx[j] : idx[0];     // clamp: L1-hit re-read
                float t = emb[(size_t)e * 256 + tid];
                acc += (j < len) ? t : 0.f;
            }
        } else {
            for (int j = 0; j < len; ++j)
                acc += emb[(size_t)pp[j] * 256 + tid];
        }
        out[2 + tid] = acc / (float)len;
    }
    if (tid == 0) { out[0] = (float)p; out[1] = s_logprob; }
}

extern "C" void kernel_launch(void* const* d_in, const int* in_sizes, int n_in,
                              void* d_out, int out_size, void* d_ws, size_t ws_size,
                              hipStream_t stream) {
    const float* emb       = (const float*)d_in[0];   // [n_edges, 256]
    const int*   paths     = (const int*)  d_in[1];   // [n_paths, max_len]
    const int*   path_lens = (const int*)  d_in[2];   // [n_paths]
    const int*   path_mask = (const int*)  d_in[3];   // [n_paths]
    const float* W         = (const float*)d_in[4];   // [256]
    const float* b         = (const float*)d_in[5];   // [1]

    int hidden  = in_sizes[4];                 // 256
    int n_edges = in_sizes[0] / hidden;        // 100000
    int n_paths = in_sizes[2];                 // 20000
    int max_len = in_sizes[1] / n_paths;       // 16

    // workspace layout
    float* s       = (float*)d_ws;             // [n_edges]  (400 KB)
    float* logits  = s + n_edges;              // [n_paths]  (80 KB)
    int*   counter = (int*)(logits + n_paths); // [1] (unused on fast path)

    // K1: one wave per edge row -> 4 waves/block, 6250 blocks (BW-saturating)
    int blocks1 = (n_edges * 64 + 255) / 256;
    k_edge_dot<<<blocks1, 256, 0, stream>>>(emb, W, s, counter, n_edges);

    // K2: one thread per path, one wave per block -> 313 blocks over 256 CUs
    int blocks2 = (n_paths + 63) / 64;
    if (max_len == 16)
        k_logits16<<<blocks2, 64, 0, stream>>>(s, paths, path_lens, path_mask,
                                               b, logits, n_paths);
    else
        k_logits_gen<<<blocks2, 64, 0, stream>>>(s, paths, path_lens, path_mask,
                                                 b, logits, n_paths, max_len);

    // K3: single-block finalization (argmax + logsumexp + z with load ILP)
    k_final<<<1, 1024, 0, stream>>>(logits, emb, paths, path_lens,
                                    (float*)d_out, n_paths, max_len);
}